// Round 1
// baseline (337.722 us; speedup 1.0000x reference)
//
#include <hip/hip_runtime.h>

// Problem constants (from reference): B,J,C,H,W = 16,16,64,256,256
#define NB 16
#define NJ 16
#define NC 64
#define NHW (256 * 256)   // 65536 spatial elements per (b,j) heatmap channel

// ---------------------------------------------------------------------------
// Kernel 1: per-(b,j) argmax over HW=65536 floats.
// Grid: B*J = 256 blocks, 1024 threads (16 waves). Each thread does 16
// float4 loads (coalesced, 16B/lane). First-occurrence tie-break:
// strict '>' within a thread (indices increase), min-index on equality
// across lanes/waves.
// ---------------------------------------------------------------------------
__global__ __launch_bounds__(1024) void argmax_kernel(
    const float* __restrict__ heatmap, int* __restrict__ idx_out) {
  const int bj = blockIdx.x;  // 0..255
  const float4* __restrict__ p4 =
      (const float4*)(heatmap + (size_t)bj * NHW);  // 16384 float4s
  const int t = threadIdx.x;  // 0..1023

  float best = -INFINITY;
  int besti = 0;
#pragma unroll
  for (int i = 0; i < 16; ++i) {
    const int k = t + i * 1024;  // float4 index, increasing per thread
    const float4 v = p4[k];
    const int base = 4 * k;
    if (v.x > best) { best = v.x; besti = base; }
    if (v.y > best) { best = v.y; besti = base + 1; }
    if (v.z > best) { best = v.z; besti = base + 2; }
    if (v.w > best) { best = v.w; besti = base + 3; }
  }

  // Wave (64-lane) reduction: max value, min index on ties.
#pragma unroll
  for (int off = 32; off > 0; off >>= 1) {
    const float ov = __shfl_down(best, off);
    const int oi = __shfl_down(besti, off);
    if (ov > best || (ov == best && oi < besti)) {
      best = ov;
      besti = oi;
    }
  }

  __shared__ float sval[16];
  __shared__ int sidx[16];
  const int wave = t >> 6;
  const int lane = t & 63;
  if (lane == 0) {
    sval[wave] = best;
    sidx[wave] = besti;
  }
  __syncthreads();
  if (t == 0) {
    float bv = sval[0];
    int bi = sidx[0];
#pragma unroll
    for (int w = 1; w < 16; ++w) {
      const float v = sval[w];
      const int i = sidx[w];
      if (v > bv || (v == bv && i < bi)) {
        bv = v;
        bi = i;
      }
    }
    idx_out[bj] = bi;
  }
}

// ---------------------------------------------------------------------------
// Kernel 2: gather pred at argmax locations, MSE vs gt, mean over (j,c).
// Grid: B = 16 blocks, 256 threads. lane (t&63) = channel c; (t>>6) picks
// which group of 4 joints. sum(diff^2) / (J*C) == mean_j(mean_c(diff^2)).
// ---------------------------------------------------------------------------
__global__ __launch_bounds__(256) void loss_kernel(
    const float* __restrict__ pred, const float* __restrict__ gt,
    const int* __restrict__ idx, float* __restrict__ out) {
  const int b = blockIdx.x;
  const int t = threadIdx.x;
  const int c = t & 63;
  const int jg = t >> 6;  // 0..3

  float acc = 0.f;
#pragma unroll
  for (int jj = 0; jj < 4; ++jj) {
    const int j = jg * 4 + jj;
    const int id = idx[b * NJ + j];
    const float pv = pred[((size_t)(b * NC + c)) * NHW + id];
    const float gv = gt[(b * NJ + j) * NC + c];
    const float d = pv - gv;
    acc += d * d;
  }

#pragma unroll
  for (int off = 32; off > 0; off >>= 1) acc += __shfl_down(acc, off);

  __shared__ float s[4];
  if ((t & 63) == 0) s[t >> 6] = acc;
  __syncthreads();
  if (t == 0) {
    out[b] = (s[0] + s[1] + s[2] + s[3]) * (1.0f / (float)(NJ * NC));
  }
}

extern "C" void kernel_launch(void* const* d_in, const int* in_sizes, int n_in,
                              void* d_out, int out_size, void* d_ws,
                              size_t ws_size, hipStream_t stream) {
  const float* pred = (const float*)d_in[0];     // [B,C,H,W]
  const float* gt = (const float*)d_in[1];       // [B,J,C]
  const float* heatmap = (const float*)d_in[2];  // [B,J,H,W]
  float* out = (float*)d_out;                    // [B]
  int* idx = (int*)d_ws;                         // B*J ints scratch

  argmax_kernel<<<NB * NJ, 1024, 0, stream>>>(heatmap, idx);
  loss_kernel<<<NB, 256, 0, stream>>>(pred, gt, idx, out);
}

// Round 2
// 337.316 us; speedup vs baseline: 1.0012x; 1.0012x over previous
//
#include <hip/hip_runtime.h>

// Problem constants (from reference): B,J,C,H,W = 16,16,64,256,256
#define NB 16
#define NJ 16
#define NC 64
#define NHW (256 * 256)  // 65536 spatial elements per (b,j) heatmap channel

// ---------------------------------------------------------------------------
// Fused kernel: per-(b,j) argmax over HW, then gather pred[b,:,idx], MSE vs
// gt[b,j,:], atomicAdd partial into out[b].
// Grid: B*J = 256 blocks (1 per CU), 1024 threads (16 waves).
// Argmax: float4 coalesced loads (16B/lane), strict '>' keeps first
// occurrence within a thread; min-index on value ties across lanes/waves
// (matches jnp.argmax first-occurrence semantics).
// out[] must be zeroed before launch (hipMemsetAsync in kernel_launch);
// each block contributes sse/(J*C) so the 16 atomics per b sum to the mean.
// ---------------------------------------------------------------------------
__global__ __launch_bounds__(1024) void fused_labelloss_kernel(
    const float* __restrict__ heatmap, const float* __restrict__ pred,
    const float* __restrict__ gt, float* __restrict__ out) {
  const int bj = blockIdx.x;  // 0..255
  const int b = bj >> 4;
  const int j = bj & 15;
  const float4* __restrict__ p4 =
      (const float4*)(heatmap + (size_t)bj * NHW);  // 16384 float4s
  const int t = threadIdx.x;                        // 0..1023

  float best = -INFINITY;
  int besti = 0;
#pragma unroll
  for (int i = 0; i < 16; ++i) {
    const int k = t + i * 1024;  // float4 index, increasing per thread
    const float4 v = p4[k];
    const int base = 4 * k;
    if (v.x > best) { best = v.x; besti = base; }
    if (v.y > best) { best = v.y; besti = base + 1; }
    if (v.z > best) { best = v.z; besti = base + 2; }
    if (v.w > best) { best = v.w; besti = base + 3; }
  }

  // Wave (64-lane) reduction: max value, min index on ties.
#pragma unroll
  for (int off = 32; off > 0; off >>= 1) {
    const float ov = __shfl_down(best, off);
    const int oi = __shfl_down(besti, off);
    if (ov > best || (ov == best && oi < besti)) {
      best = ov;
      besti = oi;
    }
  }

  __shared__ float sval[16];
  __shared__ int sidx[16];
  __shared__ int final_idx;
  const int wave = t >> 6;
  const int lane = t & 63;
  if (lane == 0) {
    sval[wave] = best;
    sidx[wave] = besti;
  }
  __syncthreads();
  if (t == 0) {
    float bv = sval[0];
    int bi = sidx[0];
#pragma unroll
    for (int w = 1; w < 16; ++w) {
      const float v = sval[w];
      const int i = sidx[w];
      if (v > bv || (v == bv && i < bi)) {
        bv = v;
        bi = i;
      }
    }
    final_idx = bi;
  }
  __syncthreads();

  // Wave 0 only: gather pred[b, c=lane, final_idx], squared diff vs gt,
  // wave-reduce sum, one atomicAdd per block.
  if (t < 64) {
    const int c = t;
    const int id = final_idx;
    const float pv = pred[((size_t)(b * NC + c)) * NHW + id];
    const float gv = gt[(b * NJ + j) * NC + c];
    const float d = pv - gv;
    float acc = d * d;
#pragma unroll
    for (int off = 32; off > 0; off >>= 1) acc += __shfl_down(acc, off);
    if (t == 0) {
      atomicAdd(&out[b], acc * (1.0f / (float)(NJ * NC)));
    }
  }
}

extern "C" void kernel_launch(void* const* d_in, const int* in_sizes, int n_in,
                              void* d_out, int out_size, void* d_ws,
                              size_t ws_size, hipStream_t stream) {
  const float* pred = (const float*)d_in[0];     // [B,C,H,W]
  const float* gt = (const float*)d_in[1];       // [B,J,C]
  const float* heatmap = (const float*)d_in[2];  // [B,J,H,W]
  float* out = (float*)d_out;                    // [B]

  // Zero the accumulator (d_out is poisoned 0xAA before every launch).
  hipMemsetAsync(out, 0, (size_t)out_size * sizeof(float), stream);

  fused_labelloss_kernel<<<NB * NJ, 1024, 0, stream>>>(heatmap, pred, gt, out);
}